// Round 2
// baseline (332.461 us; speedup 1.0000x reference)
//
#include <hip/hip_runtime.h>
#include <hip/hip_bf16.h>
#include <cstdint>
#include <cmath>

typedef __bf16 bf16_t;
typedef __attribute__((ext_vector_type(8))) bf16_t bf16x8;
typedef __attribute__((ext_vector_type(4))) float f32x4;

#define AS_GLOBAL(p) ((const __attribute__((address_space(1))) void*)(p))
#define AS_LDS(p)    ((__attribute__((address_space(3))) void*)(p))

// fp32 -> bf16 RTNE
__device__ __forceinline__ unsigned short f2bf(float f) {
  unsigned u = __builtin_bit_cast(unsigned, f);
  u += 0x7FFFu + ((u >> 16) & 1u);
  return (unsigned short)(u >> 16);
}

// ---------------- convert fp32 -> bf16 (x4 vectorized), with scale ----------------
__global__ void cvt_kernel(const float* __restrict__ in, unsigned short* __restrict__ out,
                           int n4, float scale) {
  int i = blockIdx.x * blockDim.x + threadIdx.x;
  int stride = gridDim.x * blockDim.x;
  for (; i < n4; i += stride) {
    float4 v = reinterpret_cast<const float4*>(in)[i];
    ushort4 o;
    o.x = f2bf(v.x * scale);
    o.y = f2bf(v.y * scale);
    o.z = f2bf(v.z * scale);
    o.w = f2bf(v.w * scale);
    reinterpret_cast<ushort4*>(out)[i] = o;
  }
}

// ---------------- projection GEMM ----------------
// C[4096][4096] = A[4096][2048] @ B[4096][2048]^T   (bf16 storage, fp32 accum)
// A = x_bf16, B = [Wq*scale ; Wk] row-major [N,K] (K contiguous).
// 128x128 tile, BK=64, 4 waves (2x2), each wave 64x64 = 4x4 frags of 16x16x32.
// LDS linear layout (global_load_lds requires it); XOR swizzle applied on the
// GLOBAL source address and again on the ds_read address (both-sides rule).
#define PM 4096
#define PN 4096
#define PK 2048

__global__ __launch_bounds__(256) void proj_gemm(const unsigned short* __restrict__ A,
                                                 const unsigned short* __restrict__ Bm,
                                                 unsigned short* __restrict__ C) {
  __shared__ unsigned short As[128 * 64];
  __shared__ unsigned short Bs[128 * 64];
  const int tid = threadIdx.x;
  const int wave = tid >> 6, lane = tid & 63;
  const int m0 = blockIdx.y * 128;
  const int n0 = blockIdx.x * 128;
  const int wr = wave >> 1, wc = wave & 1;

  f32x4 acc[4][4] = {};

  for (int kt = 0; kt < PK; kt += 64) {
    // stage A,B tiles: each 128 rows x 128 bytes = 16KB = 16 wave-issues of 1KB; 4 per wave
    #pragma unroll
    for (int j = 0; j < 4; ++j) {
      int base = (wave * 4 + j) * 1024;       // wave-uniform LDS byte base
      int o = base + lane * 16;               // linear tile byte covered by this lane
      int row = o >> 7;                       // 128B rows (BK=64 bf16)
      int c = o & 127;
      int csrc = c ^ ((row & 7) << 4);        // pre-swizzled global source
      const char* ga = (const char*)(A + (size_t)(m0 + row) * PK + kt) + csrc;
      __builtin_amdgcn_global_load_lds(AS_GLOBAL(ga), AS_LDS((char*)As + base), 16, 0, 0);
      const char* gb = (const char*)(Bm + (size_t)(n0 + row) * PK + kt) + csrc;
      __builtin_amdgcn_global_load_lds(AS_GLOBAL(gb), AS_LDS((char*)Bs + base), 16, 0, 0);
    }
    __syncthreads();   // drains vmcnt(0) + barrier

    #pragma unroll
    for (int ks = 0; ks < 2; ++ks) {
      bf16x8 av[4], bv[4];
      const int kbyte = ks * 64 + (lane >> 4) * 16;
      #pragma unroll
      for (int i = 0; i < 4; ++i) {
        int row = wr * 64 + i * 16 + (lane & 15);
        int off = row * 128 + (kbyte ^ ((row & 7) << 4));   // swizzled read
        av[i] = *(const bf16x8*)((const char*)As + off);
      }
      #pragma unroll
      for (int j = 0; j < 4; ++j) {
        int row = wc * 64 + j * 16 + (lane & 15);
        int off = row * 128 + (kbyte ^ ((row & 7) << 4));
        bv[j] = *(const bf16x8*)((const char*)Bs + off);
      }
      #pragma unroll
      for (int i = 0; i < 4; ++i)
        #pragma unroll
        for (int j = 0; j < 4; ++j)
          acc[i][j] = __builtin_amdgcn_mfma_f32_16x16x32_bf16(av[i], bv[j], acc[i][j], 0, 0, 0);
    }
    __syncthreads();
  }

  // epilogue: C/D layout col=lane&15, row=(lane>>4)*4+reg
  #pragma unroll
  for (int i = 0; i < 4; ++i)
    #pragma unroll
    for (int j = 0; j < 4; ++j)
      #pragma unroll
      for (int r = 0; r < 4; ++r) {
        int row = m0 + wr * 64 + i * 16 + (lane >> 4) * 4 + r;
        int col = n0 + wc * 64 + j * 16 + (lane & 15);
        C[(size_t)row * PN + col] = f2bf(acc[i][j][r]);
      }
}

// ---------------- scores kernel ----------------
// For each (b,h): S[q][k] = sum_d Q[q][d] * K[k][d], D=128, out FP32 at
// out2[((b*2048+q)*16 + h)*2048 + k]. One block = 128x128 output tile.
__global__ __launch_bounds__(256) void scores_kernel(const unsigned short* __restrict__ qk,
                                                     float* __restrict__ out2) {
  __shared__ unsigned short Qs[128 * 128];
  __shared__ unsigned short Ks[128 * 128];
  const int tid = threadIdx.x;
  const int wave = tid >> 6, lane = tid & 63;
  const int ktile = blockIdx.x;
  const int qtile = blockIdx.y;
  const int bh = blockIdx.z;
  const int b = bh >> 4, h = bh & 15;
  const int wr = wave >> 1, wc = wave & 1;

  const unsigned short* qbase = qk + (size_t)(b * 2048 + qtile * 128) * 4096 + h * 128;
  const unsigned short* kbase = qk + (size_t)(b * 2048 + ktile * 128) * 4096 + 2048 + h * 128;

  // stage Q,K tiles: each 128 rows x 256 bytes = 32KB = 32 wave-issues; 8 per wave
  #pragma unroll
  for (int j = 0; j < 8; ++j) {
    int base = (wave * 8 + j) * 1024;
    int o = base + lane * 16;
    int row = o >> 8;                         // 256B rows (D=128 bf16)
    int c = o & 255;
    int csrc = c ^ ((row & 7) << 4);
    const char* gq = (const char*)(qbase + (size_t)row * 4096) + csrc;
    __builtin_amdgcn_global_load_lds(AS_GLOBAL(gq), AS_LDS((char*)Qs + base), 16, 0, 0);
    const char* gk = (const char*)(kbase + (size_t)row * 4096) + csrc;
    __builtin_amdgcn_global_load_lds(AS_GLOBAL(gk), AS_LDS((char*)Ks + base), 16, 0, 0);
  }
  __syncthreads();

  f32x4 acc[4][4] = {};
  #pragma unroll
  for (int ks = 0; ks < 4; ++ks) {
    bf16x8 av[4], bv[4];
    const int kbyte = ks * 64 + (lane >> 4) * 16;
    #pragma unroll
    for (int i = 0; i < 4; ++i) {
      int row = wr * 64 + i * 16 + (lane & 15);
      int off = row * 256 + (kbyte ^ ((row & 7) << 4));
      av[i] = *(const bf16x8*)((const char*)Qs + off);
    }
    #pragma unroll
    for (int j = 0; j < 4; ++j) {
      int row = wc * 64 + j * 16 + (lane & 15);
      int off = row * 256 + (kbyte ^ ((row & 7) << 4));
      bv[j] = *(const bf16x8*)((const char*)Ks + off);
    }
    #pragma unroll
    for (int i = 0; i < 4; ++i)
      #pragma unroll
      for (int j = 0; j < 4; ++j)
        acc[i][j] = __builtin_amdgcn_mfma_f32_16x16x32_bf16(av[i], bv[j], acc[i][j], 0, 0, 0);
  }

  float* obase = out2 + ((size_t)(b * 2048 + qtile * 128) * 16 + h) * 2048 + ktile * 128;
  const size_t qstride = (size_t)16 * 2048;   // H*S elements between q rows
  #pragma unroll
  for (int i = 0; i < 4; ++i)
    #pragma unroll
    for (int j = 0; j < 4; ++j)
      #pragma unroll
      for (int r = 0; r < 4; ++r) {
        int qrow = wr * 64 + i * 16 + (lane >> 4) * 4 + r;
        int col = wc * 64 + j * 16 + (lane & 15);
        obase[(size_t)qrow * qstride + col] = acc[i][j][r];   // fp32 store
      }
}

extern "C" void kernel_launch(void* const* d_in, const int* in_sizes, int n_in,
                              void* d_out, int out_size, void* d_ws, size_t ws_size,
                              hipStream_t stream) {
  const float* x  = (const float*)d_in[0];
  const float* Wq = (const float*)d_in[1];
  const float* Wk = (const float*)d_in[2];
  // d_in[3] = Wv: computed then discarded by the reference -> skipped entirely.

  float* out = (float*)d_out;                             // fp32 output (reference dtype)
  unsigned short* xb = (unsigned short*)d_ws;             // x as bf16      [4096][2048]
  unsigned short* wb = xb + (size_t)4096 * 2048;          // [Wq*scale; Wk] [4096][2048]
  unsigned short* qkbuf = wb + (size_t)4096 * 2048;       // Q||K           [4096][4096]

  const float scale = 1.0f / sqrtf(128.0f);

  // Output 0: attn_output = zeros, fp32, 2*2048*2048 elements (33.5 MB)
  hipMemsetAsync(d_out, 0, (size_t)2 * 2048 * 2048 * sizeof(float), stream);

  cvt_kernel<<<2048, 256, 0, stream>>>(x, xb, (2 * 2048 * 2048) / 4, 1.0f);
  cvt_kernel<<<1024, 256, 0, stream>>>(Wq, wb, (2048 * 2048) / 4, scale);
  cvt_kernel<<<1024, 256, 0, stream>>>(Wk, wb + (size_t)2048 * 2048, (2048 * 2048) / 4, 1.0f);

  proj_gemm<<<dim3(PN / 128, PM / 128), 256, 0, stream>>>(xb, wb, qkbuf);

  // Output 1: attn_weights fp32 at element offset 2*2048*2048
  scores_kernel<<<dim3(16, 16, 32), 256, 0, stream>>>(qkbuf, out + (size_t)2 * 2048 * 2048);
}

// Round 3
// 251.378 us; speedup vs baseline: 1.3226x; 1.3226x over previous
//
#include <hip/hip_runtime.h>
#include <hip/hip_bf16.h>
#include <cstdint>
#include <cmath>

typedef __bf16 bf16_t;
typedef __attribute__((ext_vector_type(8))) bf16_t bf16x8;
typedef __attribute__((ext_vector_type(4))) float f32x4;

#define AS_GLOBAL(p) ((const __attribute__((address_space(1))) void*)(p))
#define AS_LDS(p)    ((__attribute__((address_space(3))) void*)(p))

// fp32 -> bf16 RTNE
__device__ __forceinline__ unsigned short f2bf(float f) {
  unsigned u = __builtin_bit_cast(unsigned, f);
  u += 0x7FFFu + ((u >> 16) & 1u);
  return (unsigned short)(u >> 16);
}

// ---------------- fused convert fp32 -> bf16 (x4 vectorized) ----------------
// covers x (2M vec4, scale 1), Wq (1M vec4, scale 1/sqrt(128)), Wk (1M vec4, scale 1)
#define N4_X  2097152
#define N4_W  1048576
__global__ void cvt3_kernel(const float* __restrict__ x, const float* __restrict__ wq,
                            const float* __restrict__ wk, ushort4* __restrict__ xb4,
                            ushort4* __restrict__ wb4, float scale) {
  int i = blockIdx.x * blockDim.x + threadIdx.x;
  int stride = gridDim.x * blockDim.x;
  for (; i < N4_X + 2 * N4_W; i += stride) {
    const float4* src;
    ushort4* dst;
    float sc = 1.0f;
    if (i < N4_X) {
      src = reinterpret_cast<const float4*>(x) + i;
      dst = xb4 + i;
    } else if (i < N4_X + N4_W) {
      src = reinterpret_cast<const float4*>(wq) + (i - N4_X);
      dst = wb4 + (i - N4_X);
      sc = scale;
    } else {
      src = reinterpret_cast<const float4*>(wk) + (i - N4_X - N4_W);
      dst = wb4 + (i - N4_X);   // wk lands right after wq's 1M vec4s
    }
    float4 v = *src;
    ushort4 o;
    o.x = f2bf(v.x * sc);
    o.y = f2bf(v.y * sc);
    o.z = f2bf(v.z * sc);
    o.w = f2bf(v.w * sc);
    *dst = o;
  }
}

// ---------------- projection GEMM (unchanged, proven) ----------------
// C[4096][4096] = A[4096][2048] @ B[4096][2048]^T   (bf16 storage, fp32 accum)
#define PM 4096
#define PN 4096
#define PK 2048

__global__ __launch_bounds__(256) void proj_gemm(const unsigned short* __restrict__ A,
                                                 const unsigned short* __restrict__ Bm,
                                                 unsigned short* __restrict__ C) {
  __shared__ unsigned short As[128 * 64];
  __shared__ unsigned short Bs[128 * 64];
  const int tid = threadIdx.x;
  const int wave = tid >> 6, lane = tid & 63;
  const int m0 = blockIdx.y * 128;
  const int n0 = blockIdx.x * 128;
  const int wr = wave >> 1, wc = wave & 1;

  f32x4 acc[4][4] = {};

  for (int kt = 0; kt < PK; kt += 64) {
    #pragma unroll
    for (int j = 0; j < 4; ++j) {
      int base = (wave * 4 + j) * 1024;
      int o = base + lane * 16;
      int row = o >> 7;
      int c = o & 127;
      int csrc = c ^ ((row & 7) << 4);
      const char* ga = (const char*)(A + (size_t)(m0 + row) * PK + kt) + csrc;
      __builtin_amdgcn_global_load_lds(AS_GLOBAL(ga), AS_LDS((char*)As + base), 16, 0, 0);
      const char* gb = (const char*)(Bm + (size_t)(n0 + row) * PK + kt) + csrc;
      __builtin_amdgcn_global_load_lds(AS_GLOBAL(gb), AS_LDS((char*)Bs + base), 16, 0, 0);
    }
    __syncthreads();

    #pragma unroll
    for (int ks = 0; ks < 2; ++ks) {
      bf16x8 av[4], bv[4];
      const int kbyte = ks * 64 + (lane >> 4) * 16;
      #pragma unroll
      for (int i = 0; i < 4; ++i) {
        int row = wr * 64 + i * 16 + (lane & 15);
        int off = row * 128 + (kbyte ^ ((row & 7) << 4));
        av[i] = *(const bf16x8*)((const char*)As + off);
      }
      #pragma unroll
      for (int j = 0; j < 4; ++j) {
        int row = wc * 64 + j * 16 + (lane & 15);
        int off = row * 128 + (kbyte ^ ((row & 7) << 4));
        bv[j] = *(const bf16x8*)((const char*)Bs + off);
      }
      #pragma unroll
      for (int i = 0; i < 4; ++i)
        #pragma unroll
        for (int j = 0; j < 4; ++j)
          acc[i][j] = __builtin_amdgcn_mfma_f32_16x16x32_bf16(av[i], bv[j], acc[i][j], 0, 0, 0);
    }
    __syncthreads();
  }

  #pragma unroll
  for (int i = 0; i < 4; ++i)
    #pragma unroll
    for (int j = 0; j < 4; ++j)
      #pragma unroll
      for (int r = 0; r < 4; ++r) {
        int row = m0 + wr * 64 + i * 16 + (lane >> 4) * 4 + r;
        int col = n0 + wc * 64 + j * 16 + (lane & 15);
        C[(size_t)row * PN + col] = f2bf(acc[i][j][r]);
      }
}

// ---------------- scores kernel v2: persistent-Q, streaming-K, K double-buffered ----------------
// One block per (qtile, b, h): 16 x 32 = 512 blocks = 2/CU.
// Q tile (128x128 bf16) loaded ONCE into registers as MFMA A-fragments.
// K streamed through 2x32KB LDS; output written tile-by-tile (contiguous in k).
__global__ __launch_bounds__(256) void scores_kernel(const unsigned short* __restrict__ qk,
                                                     float* __restrict__ out2) {
  __shared__ unsigned short Ks[2][128 * 128];
  const int tid = threadIdx.x;
  const int wave = tid >> 6, lane = tid & 63;
  const int qtile = blockIdx.x;
  const int bh = blockIdx.y;
  const int b = bh >> 4, h = bh & 15;
  const int wr = wave >> 1, wc = wave & 1;

  const unsigned short* qbase = qk + (size_t)(b * 2048 + qtile * 128) * 4096 + h * 128;
  const unsigned short* kbase = qk + (size_t)(b * 2048) * 4096 + 2048 + h * 128;

  // ---- load Q fragments straight to registers (A-operand layout) ----
  // qv[i][ks]: rows wr*64 + i*16 + (lane&15); elements ks*32 + (lane>>4)*8
  bf16x8 qv[4][4];
  #pragma unroll
  for (int i = 0; i < 4; ++i) {
    int row = wr * 64 + i * 16 + (lane & 15);
    const unsigned short* qr = qbase + (size_t)row * 4096 + (lane >> 4) * 8;
    #pragma unroll
    for (int ks = 0; ks < 4; ++ks)
      qv[i][ks] = *(const bf16x8*)(qr + ks * 32);
  }

  // ---- stage K tile kt into LDS buffer bi (swizzled source, linear dest) ----
  auto stageK = [&](int bi, int kt) {
    const unsigned short* kb = kbase + (size_t)kt * 128 * 4096;
    #pragma unroll
    for (int j = 0; j < 8; ++j) {
      int base = (wave * 8 + j) * 1024;
      int o = base + lane * 16;
      int row = o >> 8;                       // 256B rows (D=128 bf16)
      int c = o & 255;
      int csrc = c ^ ((row & 7) << 4);
      const char* gk = (const char*)(kb + (size_t)row * 4096) + csrc;
      __builtin_amdgcn_global_load_lds(AS_GLOBAL(gk), AS_LDS((char*)Ks[bi] + base), 16, 0, 0);
    }
  };

  float* obase = out2 + ((size_t)(b * 2048 + qtile * 128) * 16 + h) * 2048;
  const size_t qstride = (size_t)16 * 2048;

  stageK(0, 0);
  __syncthreads();             // drain vmcnt(0) + barrier

  int cur = 0;
  for (int kt = 0; kt < 16; ++kt) {
    if (kt + 1 < 16) stageK(cur ^ 1, kt + 1);   // prefetch next K tile

    f32x4 acc[4][4] = {};
    #pragma unroll
    for (int ks = 0; ks < 4; ++ks) {
      bf16x8 bv[4];
      const int kbyte = ks * 64 + (lane >> 4) * 16;
      #pragma unroll
      for (int j = 0; j < 4; ++j) {
        int row = wc * 64 + j * 16 + (lane & 15);
        int off = row * 256 + (kbyte ^ ((row & 7) << 4));
        bv[j] = *(const bf16x8*)((const char*)Ks[cur] + off);
      }
      #pragma unroll
      for (int i = 0; i < 4; ++i)
        #pragma unroll
        for (int j = 0; j < 4; ++j)
          acc[i][j] = __builtin_amdgcn_mfma_f32_16x16x32_bf16(qv[i][ks], bv[j], acc[i][j], 0, 0, 0);
    }

    // store this 128x128 fp32 tile
    #pragma unroll
    for (int i = 0; i < 4; ++i)
      #pragma unroll
      for (int j = 0; j < 4; ++j)
        #pragma unroll
        for (int r = 0; r < 4; ++r) {
          int qrow = wr * 64 + i * 16 + (lane >> 4) * 4 + r;
          int col = kt * 128 + wc * 64 + j * 16 + (lane & 15);
          obase[(size_t)qrow * qstride + col] = acc[i][j][r];
        }

    __syncthreads();           // drains prefetch vmcnt(0); buffer ready
    cur ^= 1;
  }
}

extern "C" void kernel_launch(void* const* d_in, const int* in_sizes, int n_in,
                              void* d_out, int out_size, void* d_ws, size_t ws_size,
                              hipStream_t stream) {
  const float* x  = (const float*)d_in[0];
  const float* Wq = (const float*)d_in[1];
  const float* Wk = (const float*)d_in[2];
  // d_in[3] = Wv: computed then discarded by the reference -> skipped entirely.

  float* out = (float*)d_out;                             // fp32 output
  unsigned short* xb = (unsigned short*)d_ws;             // x as bf16      [4096][2048]
  unsigned short* wb = xb + (size_t)4096 * 2048;          // [Wq*scale; Wk] [4096][2048]
  unsigned short* qkbuf = wb + (size_t)4096 * 2048;       // Q||K           [4096][4096]

  const float scale = 1.0f / sqrtf(128.0f);

  // Output 0: attn_output = zeros, fp32, 2*2048*2048 elements (33.5 MB)
  hipMemsetAsync(d_out, 0, (size_t)2 * 2048 * 2048 * sizeof(float), stream);

  cvt3_kernel<<<2048, 256, 0, stream>>>(x, Wq, Wk, (ushort4*)xb, (ushort4*)wb, scale);

  proj_gemm<<<dim3(PN / 128, PM / 128), 256, 0, stream>>>(xb, wb, qkbuf);

  // Output 1: attn_weights fp32 at element offset 2*2048*2048
  scores_kernel<<<dim3(16, 32), 256, 0, stream>>>(qkbuf, out + (size_t)2 * 2048 * 2048);
}

// Round 4
// 251.243 us; speedup vs baseline: 1.3233x; 1.0005x over previous
//
#include <hip/hip_runtime.h>
#include <hip/hip_bf16.h>
#include <cstdint>
#include <cmath>

typedef __bf16 bf16_t;
typedef __attribute__((ext_vector_type(8))) bf16_t bf16x8;
typedef __attribute__((ext_vector_type(4))) float f32x4;

#define AS_GLOBAL(p) ((const __attribute__((address_space(1))) void*)(p))
#define AS_LDS(p)    ((__attribute__((address_space(3))) void*)(p))

// fp32 -> bf16 RTNE
__device__ __forceinline__ unsigned short f2bf(float f) {
  unsigned u = __builtin_bit_cast(unsigned, f);
  u += 0x7FFFu + ((u >> 16) & 1u);
  return (unsigned short)(u >> 16);
}

// ---------------- fused convert fp32 -> bf16 (x4 vectorized) ----------------
// covers x (2M vec4, scale 1), Wq (1M vec4, scale 1/sqrt(128)), Wk (1M vec4, scale 1)
#define N4_X  2097152
#define N4_W  1048576
__global__ void cvt3_kernel(const float* __restrict__ x, const float* __restrict__ wq,
                            const float* __restrict__ wk, ushort4* __restrict__ xb4,
                            ushort4* __restrict__ wb4, float scale) {
  int i = blockIdx.x * blockDim.x + threadIdx.x;
  int stride = gridDim.x * blockDim.x;
  for (; i < N4_X + 2 * N4_W; i += stride) {
    const float4* src;
    ushort4* dst;
    float sc = 1.0f;
    if (i < N4_X) {
      src = reinterpret_cast<const float4*>(x) + i;
      dst = xb4 + i;
    } else if (i < N4_X + N4_W) {
      src = reinterpret_cast<const float4*>(wq) + (i - N4_X);
      dst = wb4 + (i - N4_X);
      sc = scale;
    } else {
      src = reinterpret_cast<const float4*>(wk) + (i - N4_X - N4_W);
      dst = wb4 + (i - N4_X);   // wk lands right after wq's 1M vec4s
    }
    float4 v = *src;
    ushort4 o;
    o.x = f2bf(v.x * sc);
    o.y = f2bf(v.y * sc);
    o.z = f2bf(v.z * sc);
    o.w = f2bf(v.w * sc);
    *dst = o;
  }
}

// ---------------- projection GEMM (unchanged, proven) ----------------
// C[4096][4096] = A[4096][2048] @ B[4096][2048]^T   (bf16 storage, fp32 accum)
#define PM 4096
#define PN 4096
#define PK 2048

__global__ __launch_bounds__(256) void proj_gemm(const unsigned short* __restrict__ A,
                                                 const unsigned short* __restrict__ Bm,
                                                 unsigned short* __restrict__ C) {
  __shared__ unsigned short As[128 * 64];
  __shared__ unsigned short Bs[128 * 64];
  const int tid = threadIdx.x;
  const int wave = tid >> 6, lane = tid & 63;
  const int m0 = blockIdx.y * 128;
  const int n0 = blockIdx.x * 128;
  const int wr = wave >> 1, wc = wave & 1;

  f32x4 acc[4][4] = {};

  for (int kt = 0; kt < PK; kt += 64) {
    #pragma unroll
    for (int j = 0; j < 4; ++j) {
      int base = (wave * 4 + j) * 1024;
      int o = base + lane * 16;
      int row = o >> 7;
      int c = o & 127;
      int csrc = c ^ ((row & 7) << 4);
      const char* ga = (const char*)(A + (size_t)(m0 + row) * PK + kt) + csrc;
      __builtin_amdgcn_global_load_lds(AS_GLOBAL(ga), AS_LDS((char*)As + base), 16, 0, 0);
      const char* gb = (const char*)(Bm + (size_t)(n0 + row) * PK + kt) + csrc;
      __builtin_amdgcn_global_load_lds(AS_GLOBAL(gb), AS_LDS((char*)Bs + base), 16, 0, 0);
    }
    __syncthreads();

    #pragma unroll
    for (int ks = 0; ks < 2; ++ks) {
      bf16x8 av[4], bv[4];
      const int kbyte = ks * 64 + (lane >> 4) * 16;
      #pragma unroll
      for (int i = 0; i < 4; ++i) {
        int row = wr * 64 + i * 16 + (lane & 15);
        int off = row * 128 + (kbyte ^ ((row & 7) << 4));
        av[i] = *(const bf16x8*)((const char*)As + off);
      }
      #pragma unroll
      for (int j = 0; j < 4; ++j) {
        int row = wc * 64 + j * 16 + (lane & 15);
        int off = row * 128 + (kbyte ^ ((row & 7) << 4));
        bv[j] = *(const bf16x8*)((const char*)Bs + off);
      }
      #pragma unroll
      for (int i = 0; i < 4; ++i)
        #pragma unroll
        for (int j = 0; j < 4; ++j)
          acc[i][j] = __builtin_amdgcn_mfma_f32_16x16x32_bf16(av[i], bv[j], acc[i][j], 0, 0, 0);
    }
    __syncthreads();
  }

  #pragma unroll
  for (int i = 0; i < 4; ++i)
    #pragma unroll
    for (int j = 0; j < 4; ++j)
      #pragma unroll
      for (int r = 0; r < 4; ++r) {
        int row = m0 + wr * 64 + i * 16 + (lane >> 4) * 4 + r;
        int col = n0 + wc * 64 + j * 16 + (lane & 15);
        C[(size_t)row * PN + col] = f2bf(acc[i][j][r]);
      }
}

// ---------------- scores kernel v3: persistent-Q, streaming-K, store-after-barrier ----------------
// One block per (qtile, b, h): 16 x 32 = 512 blocks = 2/CU.
// Q tile (128x128 bf16) loaded ONCE into registers as MFMA A-fragments.
// K streamed through 2x32KB LDS. KEY CHANGE vs v2: output stores are issued
// AFTER the per-kt __syncthreads, so the barrier's vmcnt(0) drain only covers
// this iter's 8 stage-loads (+ prev-iter stores that already had a full
// compute phase to drain). Stores overlap the NEXT iteration's stage+compute
// instead of serializing against the barrier.
__global__ __launch_bounds__(256) void scores_kernel(const unsigned short* __restrict__ qk,
                                                     float* __restrict__ out2) {
  __shared__ unsigned short Ks[2][128 * 128];
  const int tid = threadIdx.x;
  const int wave = tid >> 6, lane = tid & 63;
  const int qtile = blockIdx.x;
  const int bh = blockIdx.y;
  const int b = bh >> 4, h = bh & 15;
  const int wr = wave >> 1, wc = wave & 1;

  const unsigned short* qbase = qk + (size_t)(b * 2048 + qtile * 128) * 4096 + h * 128;
  const unsigned short* kbase = qk + (size_t)(b * 2048) * 4096 + 2048 + h * 128;

  // ---- load Q fragments straight to registers (A-operand layout) ----
  bf16x8 qv[4][4];
  #pragma unroll
  for (int i = 0; i < 4; ++i) {
    int row = wr * 64 + i * 16 + (lane & 15);
    const unsigned short* qr = qbase + (size_t)row * 4096 + (lane >> 4) * 8;
    #pragma unroll
    for (int ks = 0; ks < 4; ++ks)
      qv[i][ks] = *(const bf16x8*)(qr + ks * 32);
  }

  // ---- stage K tile kt into LDS buffer bi (swizzled source, linear dest) ----
  auto stageK = [&](int bi, int kt) {
    const unsigned short* kb = kbase + (size_t)kt * 128 * 4096;
    #pragma unroll
    for (int j = 0; j < 8; ++j) {
      int base = (wave * 8 + j) * 1024;
      int o = base + lane * 16;
      int row = o >> 8;                       // 256B rows (D=128 bf16)
      int c = o & 255;
      int csrc = c ^ ((row & 7) << 4);
      const char* gk = (const char*)(kb + (size_t)row * 4096) + csrc;
      __builtin_amdgcn_global_load_lds(AS_GLOBAL(gk), AS_LDS((char*)Ks[bi] + base), 16, 0, 0);
    }
  };

  float* obase = out2 + ((size_t)(b * 2048 + qtile * 128) * 16 + h) * 2048;
  const size_t qstride = (size_t)16 * 2048;

  stageK(0, 0);
  __syncthreads();             // drain vmcnt(0) + barrier

  int cur = 0;
  for (int kt = 0; kt < 16; ++kt) {
    if (kt + 1 < 16) stageK(cur ^ 1, kt + 1);   // prefetch next K tile

    f32x4 acc[4][4] = {};
    #pragma unroll
    for (int ks = 0; ks < 4; ++ks) {
      bf16x8 bv[4];
      const int kbyte = ks * 64 + (lane >> 4) * 16;
      #pragma unroll
      for (int j = 0; j < 4; ++j) {
        int row = wc * 64 + j * 16 + (lane & 15);
        int off = row * 256 + (kbyte ^ ((row & 7) << 4));
        bv[j] = *(const bf16x8*)((const char*)Ks[cur] + off);
      }
      #pragma unroll
      for (int i = 0; i < 4; ++i)
        #pragma unroll
        for (int j = 0; j < 4; ++j)
          acc[i][j] = __builtin_amdgcn_mfma_f32_16x16x32_bf16(qv[i][ks], bv[j], acc[i][j], 0, 0, 0);
    }

    __syncthreads();           // waits: this iter's stage loads (+ long-in-flight prev stores)

    // store this 128x128 fp32 tile — drains during NEXT iter's stage+compute
    #pragma unroll
    for (int i = 0; i < 4; ++i)
      #pragma unroll
      for (int j = 0; j < 4; ++j)
        #pragma unroll
        for (int r = 0; r < 4; ++r) {
          int qrow = wr * 64 + i * 16 + (lane >> 4) * 4 + r;
          int col = kt * 128 + wc * 64 + j * 16 + (lane & 15);
          obase[(size_t)qrow * qstride + col] = acc[i][j][r];
        }

    cur ^= 1;
  }
}

extern "C" void kernel_launch(void* const* d_in, const int* in_sizes, int n_in,
                              void* d_out, int out_size, void* d_ws, size_t ws_size,
                              hipStream_t stream) {
  const float* x  = (const float*)d_in[0];
  const float* Wq = (const float*)d_in[1];
  const float* Wk = (const float*)d_in[2];
  // d_in[3] = Wv: computed then discarded by the reference -> skipped entirely.

  float* out = (float*)d_out;                             // fp32 output
  unsigned short* xb = (unsigned short*)d_ws;             // x as bf16      [4096][2048]
  unsigned short* wb = xb + (size_t)4096 * 2048;          // [Wq*scale; Wk] [4096][2048]
  unsigned short* qkbuf = wb + (size_t)4096 * 2048;       // Q||K           [4096][4096]

  const float scale = 1.0f / sqrtf(128.0f);

  // Output 0: attn_output = zeros, fp32, 2*2048*2048 elements (33.5 MB)
  hipMemsetAsync(d_out, 0, (size_t)2 * 2048 * 2048 * sizeof(float), stream);

  cvt3_kernel<<<2048, 256, 0, stream>>>(x, Wq, Wk, (ushort4*)xb, (ushort4*)wb, scale);

  proj_gemm<<<dim3(PN / 128, PM / 128), 256, 0, stream>>>(xb, wb, qkbuf);

  // Output 1: attn_weights fp32 at element offset 2*2048*2048
  scores_kernel<<<dim3(16, 32), 256, 0, stream>>>(qkbuf, out + (size_t)2 * 2048 * 2048);
}